// Round 15
// baseline (130.941 us; speedup 1.0000x reference)
//
#include <hip/hip_runtime.h>
#include <hip/hip_bf16.h>

#define NB 2
#define ND 8
#define NHH 56
#define NWW 56
#define NC 128
#define NHEAD 4
#define DHEAD 32
#define NSEQ 392            // 8*7*7
#define NWIN 128            // 2*8*8
#define NTOK (NB*ND*NHH*NWW) // 50176
#define NHID 512
#define EPSV 1e-5f
#define PIECE 12544          // hid piece rows (4 pieces of 12544*512 bf16)
#define VSTR 420             // V LDS stride (210 dwords ≡ 18 mod 32 -> 2-way, free)

typedef unsigned int uint32;
typedef __attribute__((ext_vector_type(8))) short bf16x8;
typedef __attribute__((ext_vector_type(4))) float f32x4;
typedef __attribute__((ext_vector_type(16))) float f32x16;

__device__ __forceinline__ short f2bf(float x) {
  __hip_bfloat16 h = __float2bfloat16(x);
  return *reinterpret_cast<short*>(&h);
}
__device__ __forceinline__ float bflo(uint32 u) { return __uint_as_float(u << 16); }
__device__ __forceinline__ float bfhi(uint32 u) { return __uint_as_float(u & 0xffff0000u); }
__device__ __forceinline__ float fexp2(float x) {
  float e; asm("v_exp_f32 %0, %1" : "=v"(e) : "v"(x)); return e;
}

// windowed token index -> source spatial token index
__device__ __forceinline__ int win_to_src(int grow) {
  int win = grow / NSEQ, n = grow % NSEQ;
  int b = win >> 6, gh = (win >> 3) & 7, gw = win & 7;
  int d = n / 49, rem = n % 49;
  int p = rem / 7, q = rem % 7;
  int h = p * 8 + gh, w = q * 8 + gw;
  return ((b * ND + d) * NHH + h) * NWW + w;
}

#define GLDS(gp, lp) \
  __builtin_amdgcn_global_load_lds( \
      (const __attribute__((address_space(1))) void*)(gp), \
      (__attribute__((address_space(3))) void*)(lp), 16, 0, 0)

// ---- merged prep: blocks [0,768) convert weights (pre-swizzled bf16);
//      blocks [768,1792) do LayerNorm1 on WINDOWED rows -> swizzled bf16 ------
__global__ __launch_bounds__(256) void k_prep(
    const float* __restrict__ qkvw, const float* __restrict__ projw,
    const float* __restrict__ fc1w, const float* __restrict__ fc2w,
    short* __restrict__ wout,
    const float* __restrict__ xin, const float* __restrict__ g,
    const float* __restrict__ bsh, short* __restrict__ xout) {
  if (blockIdx.x < 768) {
    int i = blockIdx.x * 256 + threadIdx.x;   // 196608 total
    float v; int n, k, K, base;
    if (i < 49152)       { v = qkvw[i];          n = i >> 7;          k = i & 127;   K = 128; base = 0; }
    else if (i < 65536)  { int l = i - 49152;  v = projw[l]; n = l >> 7; k = l & 127; K = 128; base = 49152; }
    else if (i < 131072) { int l = i - 65536;  v = fc1w[l];  n = l >> 7; k = l & 127; K = 128; base = 65536; }
    else                 { int l = i - 131072; v = fc2w[l];  n = l >> 9; k = l & 511; K = 512; base = 131072; }
    int k2 = (((k >> 3) ^ (n & 7)) << 3) | (k & 7);
    wout[base + n * K + k2] = f2bf(v);
    return;
  }
  int w = threadIdx.x >> 6, lane = threadIdx.x & 63;
  float g0 = g[2 * lane], g1 = g[2 * lane + 1];
  float b0 = bsh[2 * lane], b1 = bsh[2 * lane + 1];
  for (int r = (blockIdx.x - 768) * 4 + w; r < NTOK; r += 4096) {
    int src = win_to_src(r);
    float2 v = *(const float2*)(xin + (long)src * NC + lane * 2);
    float s = v.x + v.y, s2 = v.x * v.x + v.y * v.y;
    #pragma unroll
    for (int m = 1; m < 64; m <<= 1) { s += __shfl_xor(s, m); s2 += __shfl_xor(s2, m); }
    float mu = s * (1.f / NC);
    float var = s2 * (1.f / NC) - mu * mu;
    float rr = rsqrtf(var + EPSV);
    uint32 p0 = (unsigned short)f2bf((v.x - mu) * rr * g0 + b0);
    uint32 p1 = (unsigned short)f2bf((v.y - mu) * rr * g1 + b1);
    int pos = (((lane >> 2) ^ (r & 7)) << 4) + ((lane & 3) << 2);  // byte in row
    *(uint32*)((char*)xout + (long)r * 256 + pos) = p0 | (p1 << 16);
  }
}

// ---- depthwise 3x3 + x residual; 8 ch/thread, uint4 loads; bf16 out ---------
__global__ void k_dwconv(const short* __restrict__ xn, const float* __restrict__ xorig,
                         const float* __restrict__ wgt, const float* __restrict__ bias,
                         short* __restrict__ out) {
  int idx = blockIdx.x * 256 + threadIdx.x;       // over NTOK*16
  int c = idx & 15;                                // 8-channel chunk
  int wr = idx >> 4;                               // windowed row
  int win = wr / NSEQ, n = wr % NSEQ;
  int b = win >> 6, gh = (win >> 3) & 7, gw = win & 7;
  int d = n / 49, rem = n % 49;
  int p = rem / 7, q = rem % 7;
  int h = p * 8 + gh, w = q * 8 + gw;
  int bd = b * ND + d;
  float acc[8];
  {
    float4 b0 = *(const float4*)(bias + 8 * c);
    float4 b1 = *(const float4*)(bias + 8 * c + 4);
    acc[0] = b0.x; acc[1] = b0.y; acc[2] = b0.z; acc[3] = b0.w;
    acc[4] = b1.x; acc[5] = b1.y; acc[6] = b1.z; acc[7] = b1.w;
  }
  #pragma unroll
  for (int kh = 0; kh < 3; kh++) {
    int hh = h + kh - 1;
    if (hh < 0 || hh >= NHH) continue;
    #pragma unroll
    for (int kw = 0; kw < 3; kw++) {
      int ww = w + kw - 1;
      if (ww < 0 || ww >= NWW) continue;
      int wr2 = ((b << 6) + ((hh & 7) << 3) + (ww & 7)) * NSEQ
              + d * 49 + (hh >> 3) * 7 + (ww >> 3);
      int bo = (c ^ (wr2 & 7)) << 4;               // bit3 of c passes through
      uint4 u = *(const uint4*)((const char*)xn + (long)wr2 * 256 + bo);
      unsigned short* us = (unsigned short*)&u;
      const float* wp = wgt + (kh * 3 + kw) * NC + 8 * c;
      float4 w0 = *(const float4*)(wp);
      float4 w1 = *(const float4*)(wp + 4);
      float wv[8] = {w0.x, w0.y, w0.z, w0.w, w1.x, w1.y, w1.z, w1.w};
      #pragma unroll
      for (int e = 0; e < 8; e++) acc[e] += bflo((uint32)us[e]) * wv[e];
    }
  }
  int src = (bd * NHH + h) * NWW + w;
  float4 x0 = *(const float4*)(xorig + ((long)src << 7) + 8 * c);
  float4 x1 = *(const float4*)(xorig + ((long)src << 7) + 8 * c + 4);
  float xv[8] = {x0.x, x0.y, x0.z, x0.w, x1.x, x1.y, x1.z, x1.w};
  short ov[8];
  #pragma unroll
  for (int e = 0; e < 8; e++) ov[e] = f2bf(acc[e] + xv[e]);
  *(uint4*)(out + ((long)wr << 7) + 8 * c) = *(uint4*)ov;
}

// ------------- MFMA GEMM: BM=64 x 128 tile, K=128, DOUBLE-BUFFERED (fc2 style)
// NT>1: 1D grid, XCD-aware decode — NT n-tiles sharing an A-panel co-locate.
// MODE 0: qkv — Q(scaled*log2e)/K/V all [wh][tok][32] bf16
// MODE 1: proj — x1 = xsum16 + bias + val -> O0 bf16 swz; fused LN2 -> O1 swz
// MODE 2: fc1 — tanh-gelu -> hid pieces h0..h3 (row-swizzled)
template <int BM, int NT, int NDIM, int KDIM, int MODE>
__global__ __launch_bounds__(256) void k_gemm_mfma(
    const short* __restrict__ A, const short* __restrict__ Wb,
    const float* __restrict__ bias, const short* __restrict__ xsum16,
    const float* __restrict__ g2, const float* __restrict__ b2,
    short* __restrict__ h0, short* __restrict__ h1,
    short* __restrict__ h2p, short* __restrict__ h3,
    void* __restrict__ O0, void* __restrict__ O1, void* __restrict__ O2) {
  static_assert(BM == 64 && KDIM == 128, "dbuf template tuned for BM=64,K=128");
  constexpr int ABYTES = BM * 128;          // 8K A-tile bytes per BK=64 step
  __shared__ char S[2][ABYTES + 16384];     // dbuf: A 8K | B 16K each
  int tid = threadIdx.x;
  int m0, n0;
  if constexpr (NT > 1) {
    int bid = blockIdx.x;
    int xcd = bid & 7, slot = bid >> 3;
    int mq = slot / NT, nt = slot - mq * NT;
    m0 = (mq * 8 + xcd) * BM;
    n0 = nt * 128;
  } else {
    m0 = blockIdx.x * BM;
    n0 = 0;
  }
  int lane = tid & 63, w = tid >> 6;
  int wm = w & 1, wn = w >> 1;
  int c16 = lane & 15, g = lane >> 4;

  f32x4 acc[2][4];
  #pragma unroll
  for (int i = 0; i < 2; i++)
    #pragma unroll
    for (int j = 0; j < 4; j++) acc[i][j] = f32x4{0.f, 0.f, 0.f, 0.f};

  // 6 loads/thread per stage: 2 A then 4 B (in-order completion for vmcnt)
#define G_STAGE(ks, buf) do {                                                 \
    int k0_ = (ks) * 64;                                                      \
    _Pragma("unroll")                                                         \
    for (int i_ = 0; i_ < 2; i_++) {                                          \
      int idx_ = tid + i_ * 256;                                              \
      int row_ = idx_ >> 3, colq_ = idx_ & 7;                                 \
      GLDS(A + (long)(m0 + row_) * KDIM + k0_ + colq_ * 8,                    \
           S[buf] + (idx_ << 4));                                             \
    }                                                                         \
    _Pragma("unroll")                                                         \
    for (int i_ = 0; i_ < 4; i_++) {                                          \
      int idx_ = tid + i_ * 256;                                              \
      int row_ = idx_ >> 3, colq_ = idx_ & 7;                                 \
      GLDS(Wb + (long)(n0 + row_) * KDIM + k0_ + colq_ * 8,                   \
           S[buf] + ABYTES + (idx_ << 4));                                    \
    }                                                                         \
  } while (0)

  G_STAGE(0, 0);
  #pragma unroll
  for (int ks = 0; ks < 2; ks++) {
    int cur = ks & 1;
    if (ks < 1) {
      G_STAGE(1, 1);
      asm volatile("s_waitcnt vmcnt(6)" ::: "memory");
    } else {
      asm volatile("s_waitcnt vmcnt(0)" ::: "memory");
    }
    __builtin_amdgcn_s_barrier();
    __builtin_amdgcn_sched_barrier(0);
    #pragma unroll
    for (int kk = 0; kk < 2; kk++) {
      bf16x8 af[2], bfr[4];
      #pragma unroll
      for (int i = 0; i < 2; i++) {
        int ra = wm * 32 + i * 16 + c16;
        int ba = (ra << 7) + ((g + kk * 4) << 4); ba ^= ((ra & 7) << 4);
        af[i] = *(const bf16x8*)(S[cur] + ba);
      }
      #pragma unroll
      for (int j = 0; j < 4; j++) {
        int rb = wn * 64 + j * 16 + c16;
        int bb = (rb << 7) + ((g + kk * 4) << 4); bb ^= ((rb & 7) << 4);
        bfr[j] = *(const bf16x8*)(S[cur] + ABYTES + bb);
      }
      #pragma unroll
      for (int i = 0; i < 2; i++)
        #pragma unroll
        for (int j = 0; j < 4; j++)
          acc[i][j] = __builtin_amdgcn_mfma_f32_16x16x32_bf16(af[i], bfr[j], acc[i][j], 0, 0, 0);
    }
    __builtin_amdgcn_s_barrier();            // all waves done with S[cur]
    __builtin_amdgcn_sched_barrier(0);
  }
#undef G_STAGE

  // ---- write bf16 C tile into S[0] with row-XOR chunk swizzle ----
  short* X1 = (short*)S[0];
  float qscale = (MODE == 0 && n0 == 0) ? 0.2550348658f : 1.0f;
  #pragma unroll
  for (int i = 0; i < 2; i++) {
    #pragma unroll
    for (int r = 0; r < 4; r++) {
      int row = wm * 32 + i * 16 + g * 4 + r;
      int sw7 = row & 7;
      #pragma unroll
      for (int j = 0; j < 4; j++) {
        int nl = wn * 64 + j * 16 + c16;
        float v = acc[i][j][r] + bias[n0 + nl];
        if constexpr (MODE == 2) {
          float u = v * (0.7978845608f + 0.035677408f * v * v);
          u = fmaxf(u, -15.f);
          float t = fexp2(u * -2.885390082f);
          v = 0.5f * v * (1.f + (1.f - t) / (1.f + t));
        } else {
          v *= qscale;
        }
        int ch = nl >> 3;
        int pos = (ch & 8) | ((ch & 7) ^ sw7);
        X1[(row << 7) + (pos << 3) + (nl & 7)] = f2bf(v);
      }
    }
  }
  __syncthreads();
  // ---- read + coalesced stores: 16 lanes cover one row's 16 chunks ----
  int cc = tid & 15;
  #pragma unroll
  for (int it8 = 0; it8 < BM / 16; it8++) {
    int row = it8 * 16 + (tid >> 4);
    int sw7 = row & 7;
    int pos = (cc & 8) | ((cc & 7) ^ sw7);
    uint4 val = *(const uint4*)(X1 + (row << 7) + (pos << 3));
    if constexpr (MODE == 0) {
      int m = m0 + row;
      int win = m / NSEQ, tok = m - win * NSEQ;
      short* OUT = (short*)((n0 == 0) ? O0 : (n0 == 128) ? O1 : O2);
      int head = cc >> 2, dim0 = (cc & 3) << 3;
      *(uint4*)(OUT + ((((long)(win * NHEAD + head)) * NSEQ + tok) << 5) + dim0) = val;
    } else if constexpr (MODE == 2) {
      int pco = m0 / PIECE;
      short* hpO = (pco == 0) ? h0 : (pco == 1) ? h1 : (pco == 2) ? h2p : h3;
      int mloc = m0 - pco * PIECE + row;
      *(uint4*)(hpO + ((long)mloc << 9) + n0 + (pos << 3)) = val;  // swz pos
    } else {  // MODE 1: add xsum, LN2 stats over the 16-lane row, dual store
      long m = m0 + row;
      uint4 xs = *(const uint4*)(xsum16 + (m << 7) + (cc << 3));
      unsigned short* tv = (unsigned short*)&val;
      unsigned short* us = (unsigned short*)&xs;
      float xv[8];
      float s = 0.f, s2 = 0.f;
      #pragma unroll
      for (int e = 0; e < 8; e++) {
        xv[e] = bflo((uint32)tv[e]) + bflo((uint32)us[e]);
        s += xv[e]; s2 += xv[e] * xv[e];
      }
      #pragma unroll
      for (int mm = 1; mm < 16; mm <<= 1) { s += __shfl_xor(s, mm); s2 += __shfl_xor(s2, mm); }
      float mu = s * (1.f / NC);
      float var = s2 * (1.f / NC) - mu * mu;
      float rr2 = rsqrtf(var + EPSV);
      float4 gv0 = *(const float4*)(g2 + cc * 8);
      float4 gv1 = *(const float4*)(g2 + cc * 8 + 4);
      float4 bv0 = *(const float4*)(b2 + cc * 8);
      float4 bv1 = *(const float4*)(b2 + cc * 8 + 4);
      float gg[8] = {gv0.x, gv0.y, gv0.z, gv0.w, gv1.x, gv1.y, gv1.z, gv1.w};
      float bb[8] = {bv0.x, bv0.y, bv0.z, bv0.w, bv1.x, bv1.y, bv1.z, bv1.w};
      short xo[8], lo[8];
      #pragma unroll
      for (int e = 0; e < 8; e++) {
        xo[e] = f2bf(xv[e]);
        lo[e] = f2bf((xv[e] - mu) * rr2 * gg[e] + bb[e]);
      }
      *(uint4*)((short*)O0 + (m << 7) + (pos << 3)) = *(uint4*)xo;  // x1 swz
      *(uint4*)((short*)O1 + (m << 7) + (pos << 3)) = *(uint4*)lo;  // xm swz
    }
  }
}

// ------------- fc2: BM=64, K=512, double-buffered (counted vmcnt) -------------
__global__ __launch_bounds__(256) void k_fc2(
    const short* __restrict__ x1, const short* __restrict__ w2,
    const float* __restrict__ bias,
    const short* __restrict__ h0, const short* __restrict__ h1,
    const short* __restrict__ h2p, const short* __restrict__ h3,
    float* __restrict__ out) {
  __shared__ char S[2][24576];              // each: A 8K | B 16K
  __shared__ int asrc[64];
  int tid = threadIdx.x;
  int m0 = blockIdx.x * 64;
  int lane = tid & 63, w = tid >> 6;
  int wm = w & 1, wn = w >> 1;
  int c16 = lane & 15, g = lane >> 4;
  if (tid < 64) asrc[tid] = win_to_src(m0 + tid);
  int pc = m0 / PIECE;
  const short* hpA = (pc == 0) ? h0 : (pc == 1) ? h1 : (pc == 2) ? h2p : h3;
  int arow0 = m0 - pc * PIECE;

  f32x4 acc[2][4];
  #pragma unroll
  for (int i = 0; i < 2; i++)
    #pragma unroll
    for (int j = 0; j < 4; j++) acc[i][j] = f32x4{0.f, 0.f, 0.f, 0.f};

#define FC2_STAGE(ks, buf) do {                                               \
    int k0_ = (ks) * 64;                                                      \
    _Pragma("unroll")                                                         \
    for (int i_ = 0; i_ < 2; i_++) {                                          \
      int idx_ = tid + i_ * 256;                                              \
      int row_ = idx_ >> 3, colq_ = idx_ & 7;                                 \
      GLDS(hpA + (long)(arow0 + row_) * 512 + k0_ + colq_ * 8,                \
           S[buf] + (idx_ << 4));                                             \
    }                                                                         \
    _Pragma("unroll")                                                         \
    for (int i_ = 0; i_ < 4; i_++) {                                          \
      int idx_ = tid + i_ * 256;                                              \
      int row_ = idx_ >> 3, colq_ = idx_ & 7;                                 \
      GLDS(w2 + (long)row_ * 512 + k0_ + colq_ * 8,                           \
           S[buf] + 8192 + (idx_ << 4));                                      \
    }                                                                         \
  } while (0)

  FC2_STAGE(0, 0);
  for (int ks = 0; ks < 8; ks++) {
    int cur = ks & 1;
    if (ks < 7) FC2_STAGE(ks + 1, cur ^ 1);
    if (ks < 7) asm volatile("s_waitcnt vmcnt(6)" ::: "memory");
    else        asm volatile("s_waitcnt vmcnt(0)" ::: "memory");
    __builtin_amdgcn_s_barrier();
    __builtin_amdgcn_sched_barrier(0);
    #pragma unroll
    for (int kk = 0; kk < 2; kk++) {
      bf16x8 af[2], bfr[4];
      #pragma unroll
      for (int i = 0; i < 2; i++) {
        int ra = wm * 32 + i * 16 + c16;
        int ba = (ra << 7) + ((g + kk * 4) << 4); ba ^= ((ra & 7) << 4);
        af[i] = *(const bf16x8*)(S[cur] + ba);
      }
      #pragma unroll
      for (int j = 0; j < 4; j++) {
        int rb = wn * 64 + j * 16 + c16;
        int bb = (rb << 7) + ((g + kk * 4) << 4); bb ^= ((rb & 7) << 4);
        bfr[j] = *(const bf16x8*)(S[cur] + 8192 + bb);
      }
      #pragma unroll
      for (int i = 0; i < 2; i++)
        #pragma unroll
        for (int j = 0; j < 4; j++)
          acc[i][j] = __builtin_amdgcn_mfma_f32_16x16x32_bf16(af[i], bfr[j], acc[i][j], 0, 0, 0);
    }
    __builtin_amdgcn_s_barrier();            // all waves done with S[cur]
    __builtin_amdgcn_sched_barrier(0);
  }
#undef FC2_STAGE

  // ---- f32 out in two 64-col half-passes through S[0] ----
  float* Xf = (float*)S[0];
  #pragma unroll
  for (int h2 = 0; h2 < 2; h2++) {
    if (h2 == 1) __syncthreads();
    if (wn == h2) {
      #pragma unroll
      for (int i = 0; i < 2; i++) {
        #pragma unroll
        for (int r = 0; r < 4; r++) {
          int row = wm * 32 + i * 16 + g * 4 + r;
          int sw7 = row & 7;
          #pragma unroll
          for (int j = 0; j < 4; j++) {
            int nl = j * 16 + c16;             // 0..63 within half
            int cf = nl >> 2;                  // f32 16B chunk 0..15
            int pos = (cf & 8) | ((cf & 7) ^ sw7);
            Xf[(row << 6) + (pos << 2) + (nl & 3)] = acc[i][j][r] + bias[h2 * 64 + nl];
          }
        }
      }
    }
    __syncthreads();
    int cf = tid & 15;
    #pragma unroll
    for (int it8 = 0; it8 < 4; it8++) {
      int row = it8 * 16 + (tid >> 4);
      int sw7 = row & 7;
      int pos = (cf & 8) | ((cf & 7) ^ sw7);
      float4 vv = *(const float4*)(Xf + (row << 6) + (pos << 2));
      int cb = h2 * 8 + (cf >> 1);
      int bpos = (cb & 8) | ((cb & 7) ^ sw7);
      uint2 xu = *(const uint2*)(x1 + (((long)(m0 + row)) << 7) + (bpos << 3) + ((cf & 1) << 2));
      unsigned short* us = (unsigned short*)&xu;
      float ov[4];
      ov[0] = vv.x + bflo((uint32)us[0]);
      ov[1] = vv.y + bflo((uint32)us[1]);
      ov[2] = vv.z + bflo((uint32)us[2]);
      ov[3] = vv.w + bflo((uint32)us[3]);
      *(float4*)(out + ((long)asrc[row] << 7) + h2 * 64 + (cf << 2)) = *(float4*)ov;
    }
  }
}

// ---------- swapped-operand 32x32 MFMA attention, 13 waves, no max-track ------
// lrun is a pure sum (no rescale) -> cross-lane reduce deferred to after loop.
__global__ __launch_bounds__(832) void k_attn_mfma(
    const short* __restrict__ Q,   // [wh][n][32], pre-scaled by 1/sqrt(d)*log2e
    const short* __restrict__ Kk,  // [wh][n][32]
    const short* __restrict__ Vv,  // [wh][n][32]
    short* __restrict__ aout) {    // [wrow][128] bf16, SWIZZLED
  int wh = blockIdx.x, win = wh >> 2, head = wh & 3;
  __shared__ short Ks[NSEQ * 32];        // XOR-swizzled rows, 64 B stride
  __shared__ short Vs[32 * VSTR];        // [d][tok]; cols >=392 zero
  int tid = threadIdx.x;
  int lane = tid & 63, w = tid >> 6;     // w = 0..12 : one q-tile per wave
  int ql = lane & 31, h = lane >> 5;

  const uint4* Kg4 = (const uint4*)(Kk + (long)wh * NSEQ * DHEAD);
  for (int i = tid; i < 1568; i += 832) {
    int b = i * 16; b ^= ((b >> 6) & 7) << 4;
    *(uint4*)((char*)Ks + b) = Kg4[i];
  }
  const uint32* Vg = (const uint32*)(Vv + (long)wh * NSEQ * DHEAD);
  for (int i = tid; i < NSEQ * 16; i += 832) {
    int tok = i >> 4, dp = i & 15;
    uint32 u = Vg[i];
    Vs[(2 * dp) * VSTR + tok] = (short)(u & 0xffff);
    Vs[(2 * dp + 1) * VSTR + tok] = (short)(u >> 16);
  }
  if (tid < 224) {                        // zero pad cols 392..419 (28 per row)
    int r = tid >> 3, c7 = tid & 7;
    if (c7 < 7) *(uint2*)&Vs[r * VSTR + 392 + c7 * 4] = make_uint2(0, 0);
  }
  if (tid >= 224 && tid < 448) {
    int t2 = tid - 224;
    int r = 28 + (t2 >> 3), c7 = t2 & 7;
    if (c7 < 7 && r < 32) *(uint2*)&Vs[r * VSTR + 392 + c7 * 4] = make_uint2(0, 0);
  }
  __syncthreads();

  int q0 = w * 32;                        // tile 12 has 8 valid rows
  int qrow = q0 + ql; if (qrow > NSEQ - 1) qrow = NSEQ - 1;
  const short* Qr = Q + ((long)wh * NSEQ + qrow) * DHEAD;
  bf16x8 qf0 = *(const bf16x8*)(Qr + h * 8);
  bf16x8 qf1 = *(const bf16x8*)(Qr + 16 + h * 8);
  f32x16 o;
  #pragma unroll
  for (int r = 0; r < 16; r++) o[r] = 0.f;
  float lrun = 0.f;

  for (int c = 0; c < 13; c++) {
    int kb = c * 32;
    int krow = kb + ql;
    int sw = (krow & 7) << 4;
    int b0 = krow * 64 + h * 16;
    bf16x8 kf0 = *(const bf16x8*)((char*)Ks + (b0 ^ sw));
    bf16x8 kf1 = *(const bf16x8*)((char*)Ks + ((b0 + 32) ^ sw));
    f32x16 st;
    #pragma unroll
    for (int r = 0; r < 16; r++) st[r] = 0.f;
    __builtin_amdgcn_s_setprio(1);
    st = __builtin_amdgcn_mfma_f32_32x32x16_bf16(kf0, qf0, st, 0, 0, 0);
    st = __builtin_amdgcn_mfma_f32_32x32x16_bf16(kf1, qf1, st, 0, 0, 0);
    __builtin_amdgcn_s_setprio(0);
    if (c == 12) {
      #pragma unroll
      for (int r = 4; r < 16; r++) st[r] = -10000.f;   // exp2 -> 0
    }
    #pragma unroll
    for (int r = 0; r < 16; r++) { st[r] = fexp2(st[r]); lrun += st[r]; }
    #pragma unroll
    for (int s = 0; s < 2; s++) {
      if (s == 1 && c == 12) break;
      uint32 z0, z1, z2, z3;
      float p0 = st[8 * s + 0], p1 = st[8 * s + 1], p2 = st[8 * s + 2], p3 = st[8 * s + 3];
      float p4 = st[8 * s + 4], p5 = st[8 * s + 5], p6 = st[8 * s + 6], p7 = st[8 * s + 7];
      asm("v_cvt_pk_bf16_f32 %0, %1, %2" : "=v"(z0) : "v"(p0), "v"(p1));
      asm("v_cvt_pk_bf16_f32 %0, %1, %2" : "=v"(z1) : "v"(p2), "v"(p3));
      asm("v_cvt_pk_bf16_f32 %0, %1, %2" : "=v"(z2) : "v"(p4), "v"(p5));
      asm("v_cvt_pk_bf16_f32 %0, %1, %2" : "=v"(z3) : "v"(p6), "v"(p7));
      asm("v_permlane32_swap_b32 %0, %1" : "+v"(z0), "+v"(z2));
      asm("v_permlane32_swap_b32 %0, %1" : "+v"(z1), "+v"(z3));
      union { uint32 u[4]; bf16x8 v; } pb;
      pb.u[0] = z0; pb.u[1] = z1; pb.u[2] = z2; pb.u[3] = z3;
      bf16x8 vf = *(const bf16x8*)&Vs[ql * VSTR + kb + 16 * s + 8 * h];
      __builtin_amdgcn_s_setprio(1);
      o = __builtin_amdgcn_mfma_f32_32x32x16_bf16(vf, pb.v, o, 0, 0, 0);
      __builtin_amdgcn_s_setprio(0);
    }
  }
  lrun += __shfl_xor(lrun, 32);           // single deferred cross-lane reduce
  if (q0 + ql < NSEQ) {
    float inv = 1.0f / lrun;
    int qq = q0 + ql;
    long rowb = ((long)win * NSEQ + qq) * 256;   // byte base; (wrow&7)==(qq&7)
    int sw7 = qq & 7;
    #pragma unroll
    for (int rr = 0; rr < 8; rr++) {
      int r = 2 * rr;
      int d = (r & 3) + 8 * (r >> 2) + 4 * h;
      float a0 = o[r] * inv, a1 = o[r + 1] * inv;
      uint32 pk;
      asm("v_cvt_pk_bf16_f32 %0, %1, %2" : "=v"(pk) : "v"(a0), "v"(a1));
      int ch = head * 32 + d;
      int bo = (((ch >> 3) ^ sw7) << 4) + ((ch & 7) << 1);
      *(uint32*)((char*)aout + rowb + bo) = pk;
    }
  }
}

extern "C" void kernel_launch(void* const* d_in, const int* in_sizes, int n_in,
                              void* d_out, int out_size, void* d_ws, size_t ws_size,
                              hipStream_t stream) {
  const float* x    = (const float*)d_in[0];
  const float* n1g  = (const float*)d_in[1];
  const float* n1b  = (const float*)d_in[2];
  const float* qkvw = (const float*)d_in[3];
  const float* qkvb = (const float*)d_in[4];
  const float* projw= (const float*)d_in[5];
  const float* projb= (const float*)d_in[6];
  const float* dww  = (const float*)d_in[7];
  const float* dwb  = (const float*)d_in[8];
  const float* n2g  = (const float*)d_in[9];
  const float* n2b  = (const float*)d_in[10];
  const float* fc1w = (const float*)d_in[11];
  const float* fc1b = (const float*)d_in[12];
  const float* fc2w = (const float*)d_in[13];
  const float* fc2b = (const float*)d_in[14];

  char* ws = (char*)d_ws;
  short* wb_q = (short*)(ws + 0);              // 49152 sh
  short* wb_p = wb_q + 49152;
  short* wb_1 = wb_p + 16384;
  short* wb_2 = wb_1 + 65536;                  // end 393216 B
  short* xnb  = (short*)(ws + 393216);         // 12.8MB bf16 [-> aout -> hid p0]
  short* xs16 = (short*)(ws + 13238272);       // 12.8MB bf16 xsum [-> hid p1]
  short* Qb   = (short*)(ws + 38928384);       // 12.8MB      [-> x1]
  short* Kb   = (short*)(ws + 51773440);       // 12.8MB      [-> hid p3]
  short* Vb   = (short*)(ws + 64618496);       // 12.8MB      [-> xm]
  short* aoutb = xnb;
  short* x1b   = Qb;
  short* xmb   = Vb;
  short* hid0  = xnb;
  short* hid1  = (short*)(ws + 13238272);
  short* hid2  = (short*)(ws + 26083328);
  short* hid3  = Kb;

  k_prep<<<1792, 256, 0, stream>>>(qkvw, projw, fc1w, fc2w, wb_q, x, n1g, n1b, xnb);
  k_dwconv<<<(NTOK * 16) / 256, 256, 0, stream>>>(xnb, x, dww, dwb, xs16);
  k_gemm_mfma<64, 3, 384, 128, 0><<<2352, 256, 0, stream>>>(
      xnb, wb_q, qkvb, nullptr, nullptr, nullptr,
      nullptr, nullptr, nullptr, nullptr, Qb, Kb, Vb);
  k_attn_mfma<<<NWIN * NHEAD, 832, 0, stream>>>(Qb, Kb, Vb, aoutb);
  k_gemm_mfma<64, 1, 128, 128, 1><<<784, 256, 0, stream>>>(
      aoutb, wb_p, projb, xs16, n2g, n2b,
      nullptr, nullptr, nullptr, nullptr, x1b, xmb, nullptr);
  k_gemm_mfma<64, 4, 512, 128, 2><<<3136, 256, 0, stream>>>(
      xmb, wb_1, fc1b, nullptr, nullptr, nullptr,
      hid0, hid1, hid2, hid3, nullptr, nullptr, nullptr);
  k_fc2<<<784, 256, 0, stream>>>(
      x1b, wb_2, fc2b, hid0, hid1, hid2, hid3, (float*)d_out);
}

// Round 16
// 127.749 us; speedup vs baseline: 1.0250x; 1.0250x over previous
//
#include <hip/hip_runtime.h>
#include <hip/hip_bf16.h>

#define NB 2
#define ND 8
#define NHH 56
#define NWW 56
#define NC 128
#define NHEAD 4
#define DHEAD 32
#define NSEQ 392            // 8*7*7
#define NWIN 128            // 2*8*8
#define NTOK (NB*ND*NHH*NWW) // 50176
#define NHID 512
#define EPSV 1e-5f
#define PIECE 12544          // hid piece rows (4 pieces of 12544*512 bf16)
#define VSTR 420             // V LDS stride (210 dwords ≡ 18 mod 32 -> 2-way, free)

typedef unsigned int uint32;
typedef __attribute__((ext_vector_type(8))) short bf16x8;
typedef __attribute__((ext_vector_type(4))) float f32x4;
typedef __attribute__((ext_vector_type(16))) float f32x16;

__device__ __forceinline__ short f2bf(float x) {
  __hip_bfloat16 h = __float2bfloat16(x);
  return *reinterpret_cast<short*>(&h);
}
__device__ __forceinline__ float bflo(uint32 u) { return __uint_as_float(u << 16); }
__device__ __forceinline__ float bfhi(uint32 u) { return __uint_as_float(u & 0xffff0000u); }
__device__ __forceinline__ float fexp2(float x) {
  float e; asm("v_exp_f32 %0, %1" : "=v"(e) : "v"(x)); return e;
}

// windowed token index -> source spatial token index
__device__ __forceinline__ int win_to_src(int grow) {
  int win = grow / NSEQ, n = grow % NSEQ;
  int b = win >> 6, gh = (win >> 3) & 7, gw = win & 7;
  int d = n / 49, rem = n % 49;
  int p = rem / 7, q = rem % 7;
  int h = p * 8 + gh, w = q * 8 + gw;
  return ((b * ND + d) * NHH + h) * NWW + w;
}

#define GLDS(gp, lp) \
  __builtin_amdgcn_global_load_lds( \
      (const __attribute__((address_space(1))) void*)(gp), \
      (__attribute__((address_space(3))) void*)(lp), 16, 0, 0)

// ---- merged prep: blocks [0,768) convert weights (pre-swizzled bf16);
//      blocks [768,1792) do LayerNorm1 on WINDOWED rows -> swizzled bf16 ------
__global__ __launch_bounds__(256) void k_prep(
    const float* __restrict__ qkvw, const float* __restrict__ projw,
    const float* __restrict__ fc1w, const float* __restrict__ fc2w,
    short* __restrict__ wout,
    const float* __restrict__ xin, const float* __restrict__ g,
    const float* __restrict__ bsh, short* __restrict__ xout) {
  if (blockIdx.x < 768) {
    int i = blockIdx.x * 256 + threadIdx.x;   // 196608 total
    float v; int n, k, K, base;
    if (i < 49152)       { v = qkvw[i];          n = i >> 7;          k = i & 127;   K = 128; base = 0; }
    else if (i < 65536)  { int l = i - 49152;  v = projw[l]; n = l >> 7; k = l & 127; K = 128; base = 49152; }
    else if (i < 131072) { int l = i - 65536;  v = fc1w[l];  n = l >> 7; k = l & 127; K = 128; base = 65536; }
    else                 { int l = i - 131072; v = fc2w[l];  n = l >> 9; k = l & 511; K = 512; base = 131072; }
    int k2 = (((k >> 3) ^ (n & 7)) << 3) | (k & 7);
    wout[base + n * K + k2] = f2bf(v);
    return;
  }
  int w = threadIdx.x >> 6, lane = threadIdx.x & 63;
  float g0 = g[2 * lane], g1 = g[2 * lane + 1];
  float b0 = bsh[2 * lane], b1 = bsh[2 * lane + 1];
  for (int r = (blockIdx.x - 768) * 4 + w; r < NTOK; r += 4096) {
    int src = win_to_src(r);
    float2 v = *(const float2*)(xin + (long)src * NC + lane * 2);
    float s = v.x + v.y, s2 = v.x * v.x + v.y * v.y;
    #pragma unroll
    for (int m = 1; m < 64; m <<= 1) { s += __shfl_xor(s, m); s2 += __shfl_xor(s2, m); }
    float mu = s * (1.f / NC);
    float var = s2 * (1.f / NC) - mu * mu;
    float rr = rsqrtf(var + EPSV);
    uint32 p0 = (unsigned short)f2bf((v.x - mu) * rr * g0 + b0);
    uint32 p1 = (unsigned short)f2bf((v.y - mu) * rr * g1 + b1);
    int pos = (((lane >> 2) ^ (r & 7)) << 4) + ((lane & 3) << 2);  // byte in row
    *(uint32*)((char*)xout + (long)r * 256 + pos) = p0 | (p1 << 16);
  }
}

// ---- depthwise 3x3 + x residual; 8 ch/thread, uint4 loads; bf16 out ---------
__global__ void k_dwconv(const short* __restrict__ xn, const float* __restrict__ xorig,
                         const float* __restrict__ wgt, const float* __restrict__ bias,
                         short* __restrict__ out) {
  int idx = blockIdx.x * 256 + threadIdx.x;       // over NTOK*16
  int c = idx & 15;                                // 8-channel chunk
  int wr = idx >> 4;                               // windowed row
  int win = wr / NSEQ, n = wr % NSEQ;
  int b = win >> 6, gh = (win >> 3) & 7, gw = win & 7;
  int d = n / 49, rem = n % 49;
  int p = rem / 7, q = rem % 7;
  int h = p * 8 + gh, w = q * 8 + gw;
  int bd = b * ND + d;
  float acc[8];
  {
    float4 b0 = *(const float4*)(bias + 8 * c);
    float4 b1 = *(const float4*)(bias + 8 * c + 4);
    acc[0] = b0.x; acc[1] = b0.y; acc[2] = b0.z; acc[3] = b0.w;
    acc[4] = b1.x; acc[5] = b1.y; acc[6] = b1.z; acc[7] = b1.w;
  }
  #pragma unroll
  for (int kh = 0; kh < 3; kh++) {
    int hh = h + kh - 1;
    if (hh < 0 || hh >= NHH) continue;
    #pragma unroll
    for (int kw = 0; kw < 3; kw++) {
      int ww = w + kw - 1;
      if (ww < 0 || ww >= NWW) continue;
      int wr2 = ((b << 6) + ((hh & 7) << 3) + (ww & 7)) * NSEQ
              + d * 49 + (hh >> 3) * 7 + (ww >> 3);
      int bo = (c ^ (wr2 & 7)) << 4;               // bit3 of c passes through
      uint4 u = *(const uint4*)((const char*)xn + (long)wr2 * 256 + bo);
      unsigned short* us = (unsigned short*)&u;
      const float* wp = wgt + (kh * 3 + kw) * NC + 8 * c;
      float4 w0 = *(const float4*)(wp);
      float4 w1 = *(const float4*)(wp + 4);
      float wv[8] = {w0.x, w0.y, w0.z, w0.w, w1.x, w1.y, w1.z, w1.w};
      #pragma unroll
      for (int e = 0; e < 8; e++) acc[e] += bflo((uint32)us[e]) * wv[e];
    }
  }
  int src = (bd * NHH + h) * NWW + w;
  float4 x0 = *(const float4*)(xorig + ((long)src << 7) + 8 * c);
  float4 x1 = *(const float4*)(xorig + ((long)src << 7) + 8 * c + 4);
  float xv[8] = {x0.x, x0.y, x0.z, x0.w, x1.x, x1.y, x1.z, x1.w};
  short ov[8];
  #pragma unroll
  for (int e = 0; e < 8; e++) ov[e] = f2bf(acc[e] + xv[e]);
  *(uint4*)(out + ((long)wr << 7) + 8 * c) = *(uint4*)ov;
}

// ------------- MFMA GEMM: C[M,N] = A[M,K] * W[N,K]^T, BMx128 tile, BK=64 ------
// Single-buffered 24KB staging (6 blocks/CU) — R15 dbuf experiment showed the
// 2-K-step pipeline loses more occupancy TLP than it hides drain latency.
// NT>1: 1D grid with XCD-aware decode — the NT n-tiles sharing an A-panel get
// the same (bid&7) XCD and adjacent slots, so A re-reads hit that XCD's L2.
// MODE 0: qkv — Q(scaled*log2e)/K/V all [wh][tok][32] bf16
// MODE 1: proj — x1 = xsum16 + bias + val -> O0 bf16 swz; fused LN2 -> O1 swz
// MODE 2: fc1 — tanh-gelu -> hid pieces h0..h3 (row-swizzled)
template <int BM, int NT, int NDIM, int KDIM, int MODE>
__global__ __launch_bounds__(256) void k_gemm_mfma(
    const short* __restrict__ A, const short* __restrict__ Wb,
    const float* __restrict__ bias, const short* __restrict__ xsum16,
    const float* __restrict__ g2, const float* __restrict__ b2,
    short* __restrict__ h0, short* __restrict__ h1,
    short* __restrict__ h2p, short* __restrict__ h3,
    void* __restrict__ O0, void* __restrict__ O1, void* __restrict__ O2) {
  constexpr int ABYTES = BM * 128;          // A tile bytes per BK=64 step
  constexpr int MI = BM / 32;               // row-fragments per wave
  __shared__ char S[ABYTES + 16384];        // A | B staging; reused post-loop
  int tid = threadIdx.x;
  int m0, n0;
  if constexpr (NT > 1) {
    int bid = blockIdx.x;
    int xcd = bid & 7, slot = bid >> 3;
    int mq = slot / NT, nt = slot - mq * NT;
    m0 = (mq * 8 + xcd) * BM;
    n0 = nt * 128;
  } else {
    m0 = blockIdx.x * BM;
    n0 = 0;
  }
  int lane = tid & 63, w = tid >> 6;
  int wm = w & 1, wn = w >> 1;
  int c16 = lane & 15, g = lane >> 4;

  f32x4 acc[MI][4];
  #pragma unroll
  for (int i = 0; i < MI; i++)
    #pragma unroll
    for (int j = 0; j < 4; j++) acc[i][j] = f32x4{0.f, 0.f, 0.f, 0.f};

  const int KSTEPS = KDIM / 64;
  for (int ks = 0; ks < KSTEPS; ks++) {
    int k0 = ks * 64;
    if (ks > 0) __syncthreads();
    #pragma unroll
    for (int i = 0; i < BM / 32; i++) {      // A: BM*8 units / 256 threads
      int idx = tid + i * 256;
      int row = idx >> 3, colq = idx & 7;
      GLDS(A + (long)(m0 + row) * KDIM + k0 + colq * 8, S + (idx << 4));
    }
    #pragma unroll
    for (int i = 0; i < 4; i++) {            // B: 128 rows
      int idx = tid + i * 256;
      int row = idx >> 3, colq = idx & 7;
      GLDS(Wb + (long)(n0 + row) * KDIM + k0 + colq * 8, S + ABYTES + (idx << 4));
    }
    asm volatile("s_waitcnt vmcnt(0)" ::: "memory");
    __syncthreads();
    #pragma unroll
    for (int kk = 0; kk < 2; kk++) {
      bf16x8 af[MI], bfr[4];
      #pragma unroll
      for (int i = 0; i < MI; i++) {
        int ra = wm * (BM / 2) + i * 16 + c16;
        int ba = (ra << 7) + ((g + kk * 4) << 4); ba ^= ((ra & 7) << 4);
        af[i] = *(const bf16x8*)(S + ba);
      }
      #pragma unroll
      for (int j = 0; j < 4; j++) {
        int rb = wn * 64 + j * 16 + c16;
        int bb = (rb << 7) + ((g + kk * 4) << 4); bb ^= ((rb & 7) << 4);
        bfr[j] = *(const bf16x8*)(S + ABYTES + bb);
      }
      #pragma unroll
      for (int i = 0; i < MI; i++)
        #pragma unroll
        for (int j = 0; j < 4; j++)
          acc[i][j] = __builtin_amdgcn_mfma_f32_16x16x32_bf16(af[i], bfr[j], acc[i][j], 0, 0, 0);
    }
  }
  __syncthreads();                           // staging dead; S reusable

  // ---- write bf16 C tile into S with row-XOR chunk swizzle ----
  short* X1 = (short*)S;
  float qscale = (MODE == 0 && n0 == 0) ? 0.2550348658f : 1.0f;
  #pragma unroll
  for (int i = 0; i < MI; i++) {
    #pragma unroll
    for (int r = 0; r < 4; r++) {
      int row = wm * (BM / 2) + i * 16 + g * 4 + r;
      int sw7 = row & 7;
      #pragma unroll
      for (int j = 0; j < 4; j++) {
        int nl = wn * 64 + j * 16 + c16;
        float v = acc[i][j][r] + bias[n0 + nl];
        if constexpr (MODE == 2) {
          float u = v * (0.7978845608f + 0.035677408f * v * v);
          u = fmaxf(u, -15.f);
          float t = fexp2(u * -2.885390082f);
          v = 0.5f * v * (1.f + (1.f - t) / (1.f + t));
        } else {
          v *= qscale;
        }
        int ch = nl >> 3;
        int pos = (ch & 8) | ((ch & 7) ^ sw7);
        X1[(row << 7) + (pos << 3) + (nl & 7)] = f2bf(v);
      }
    }
  }
  __syncthreads();
  // ---- read + coalesced stores: 16 lanes cover one row's 16 chunks ----
  int cc = tid & 15;
  #pragma unroll
  for (int it8 = 0; it8 < BM / 16; it8++) {
    int row = it8 * 16 + (tid >> 4);
    int sw7 = row & 7;
    int pos = (cc & 8) | ((cc & 7) ^ sw7);
    uint4 val = *(const uint4*)(X1 + (row << 7) + (pos << 3));
    if constexpr (MODE == 0) {
      int m = m0 + row;
      int win = m / NSEQ, tok = m - win * NSEQ;
      short* OUT = (short*)((n0 == 0) ? O0 : (n0 == 128) ? O1 : O2);
      int head = cc >> 2, dim0 = (cc & 3) << 3;
      *(uint4*)(OUT + ((((long)(win * NHEAD + head)) * NSEQ + tok) << 5) + dim0) = val;
    } else if constexpr (MODE == 2) {
      int pco = m0 / PIECE;
      short* hpO = (pco == 0) ? h0 : (pco == 1) ? h1 : (pco == 2) ? h2p : h3;
      int mloc = m0 - pco * PIECE + row;
      *(uint4*)(hpO + ((long)mloc << 9) + n0 + (pos << 3)) = val;  // swz pos
    } else {  // MODE 1: add xsum, LN2 stats over the 16-lane row, dual store
      long m = m0 + row;
      uint4 xs = *(const uint4*)(xsum16 + (m << 7) + (cc << 3));
      unsigned short* tv = (unsigned short*)&val;
      unsigned short* us = (unsigned short*)&xs;
      float xv[8];
      float s = 0.f, s2 = 0.f;
      #pragma unroll
      for (int e = 0; e < 8; e++) {
        xv[e] = bflo((uint32)tv[e]) + bflo((uint32)us[e]);
        s += xv[e]; s2 += xv[e] * xv[e];
      }
      #pragma unroll
      for (int mm = 1; mm < 16; mm <<= 1) { s += __shfl_xor(s, mm); s2 += __shfl_xor(s2, mm); }
      float mu = s * (1.f / NC);
      float var = s2 * (1.f / NC) - mu * mu;
      float rr2 = rsqrtf(var + EPSV);
      float4 gv0 = *(const float4*)(g2 + cc * 8);
      float4 gv1 = *(const float4*)(g2 + cc * 8 + 4);
      float4 bv0 = *(const float4*)(b2 + cc * 8);
      float4 bv1 = *(const float4*)(b2 + cc * 8 + 4);
      float gg[8] = {gv0.x, gv0.y, gv0.z, gv0.w, gv1.x, gv1.y, gv1.z, gv1.w};
      float bb[8] = {bv0.x, bv0.y, bv0.z, bv0.w, bv1.x, bv1.y, bv1.z, bv1.w};
      short xo[8], lo[8];
      #pragma unroll
      for (int e = 0; e < 8; e++) {
        xo[e] = f2bf(xv[e]);
        lo[e] = f2bf((xv[e] - mu) * rr2 * gg[e] + bb[e]);
      }
      *(uint4*)((short*)O0 + (m << 7) + (pos << 3)) = *(uint4*)xo;  // x1 swz
      *(uint4*)((short*)O1 + (m << 7) + (pos << 3)) = *(uint4*)lo;  // xm swz
    }
  }
}

// ------------- fc2: BM=64, K=512, double-buffered (counted vmcnt) -------------
// 8 K-steps amortize the pipeline; grid 784 ≈ 3/CU so the 48KB LDS is free.
__global__ __launch_bounds__(256) void k_fc2(
    const short* __restrict__ x1, const short* __restrict__ w2,
    const float* __restrict__ bias,
    const short* __restrict__ h0, const short* __restrict__ h1,
    const short* __restrict__ h2p, const short* __restrict__ h3,
    float* __restrict__ out) {
  __shared__ char S[2][24576];              // each: A 8K | B 16K
  __shared__ int asrc[64];
  int tid = threadIdx.x;
  int m0 = blockIdx.x * 64;
  int lane = tid & 63, w = tid >> 6;
  int wm = w & 1, wn = w >> 1;
  int c16 = lane & 15, g = lane >> 4;
  if (tid < 64) asrc[tid] = win_to_src(m0 + tid);
  int pc = m0 / PIECE;
  const short* hpA = (pc == 0) ? h0 : (pc == 1) ? h1 : (pc == 2) ? h2p : h3;
  int arow0 = m0 - pc * PIECE;

  f32x4 acc[2][4];
  #pragma unroll
  for (int i = 0; i < 2; i++)
    #pragma unroll
    for (int j = 0; j < 4; j++) acc[i][j] = f32x4{0.f, 0.f, 0.f, 0.f};

#define FC2_STAGE(ks, buf) do {                                               \
    int k0_ = (ks) * 64;                                                      \
    _Pragma("unroll")                                                         \
    for (int i_ = 0; i_ < 2; i_++) {                                          \
      int idx_ = tid + i_ * 256;                                              \
      int row_ = idx_ >> 3, colq_ = idx_ & 7;                                 \
      GLDS(hpA + (long)(arow0 + row_) * 512 + k0_ + colq_ * 8,                \
           S[buf] + (idx_ << 4));                                             \
    }                                                                         \
    _Pragma("unroll")                                                         \
    for (int i_ = 0; i_ < 4; i_++) {                                          \
      int idx_ = tid + i_ * 256;                                              \
      int row_ = idx_ >> 3, colq_ = idx_ & 7;                                 \
      GLDS(w2 + (long)row_ * 512 + k0_ + colq_ * 8,                           \
           S[buf] + 8192 + (idx_ << 4));                                      \
    }                                                                         \
  } while (0)

  FC2_STAGE(0, 0);
  for (int ks = 0; ks < 8; ks++) {
    int cur = ks & 1;
    if (ks < 7) FC2_STAGE(ks + 1, cur ^ 1);
    if (ks < 7) asm volatile("s_waitcnt vmcnt(6)" ::: "memory");
    else        asm volatile("s_waitcnt vmcnt(0)" ::: "memory");
    __builtin_amdgcn_s_barrier();
    __builtin_amdgcn_sched_barrier(0);
    #pragma unroll
    for (int kk = 0; kk < 2; kk++) {
      bf16x8 af[2], bfr[4];
      #pragma unroll
      for (int i = 0; i < 2; i++) {
        int ra = wm * 32 + i * 16 + c16;
        int ba = (ra << 7) + ((g + kk * 4) << 4); ba ^= ((ra & 7) << 4);
        af[i] = *(const bf16x8*)(S[cur] + ba);
      }
      #pragma unroll
      for (int j = 0; j < 4; j++) {
        int rb = wn * 64 + j * 16 + c16;
        int bb = (rb << 7) + ((g + kk * 4) << 4); bb ^= ((rb & 7) << 4);
        bfr[j] = *(const bf16x8*)(S[cur] + 8192 + bb);
      }
      #pragma unroll
      for (int i = 0; i < 2; i++)
        #pragma unroll
        for (int j = 0; j < 4; j++)
          acc[i][j] = __builtin_amdgcn_mfma_f32_16x16x32_bf16(af[i], bfr[j], acc[i][j], 0, 0, 0);
    }
    __builtin_amdgcn_s_barrier();            // all waves done with S[cur]
    __builtin_amdgcn_sched_barrier(0);
  }
#undef FC2_STAGE

  // ---- f32 out in two 64-col half-passes through S[0] ----
  float* Xf = (float*)S[0];
  #pragma unroll
  for (int h2 = 0; h2 < 2; h2++) {
    if (h2 == 1) __syncthreads();
    if (wn == h2) {
      #pragma unroll
      for (int i = 0; i < 2; i++) {
        #pragma unroll
        for (int r = 0; r < 4; r++) {
          int row = wm * 32 + i * 16 + g * 4 + r;
          int sw7 = row & 7;
          #pragma unroll
          for (int j = 0; j < 4; j++) {
            int nl = j * 16 + c16;             // 0..63 within half
            int cf = nl >> 2;                  // f32 16B chunk 0..15
            int pos = (cf & 8) | ((cf & 7) ^ sw7);
            Xf[(row << 6) + (pos << 2) + (nl & 3)] = acc[i][j][r] + bias[h2 * 64 + nl];
          }
        }
      }
    }
    __syncthreads();
    int cf = tid & 15;
    #pragma unroll
    for (int it8 = 0; it8 < 4; it8++) {
      int row = it8 * 16 + (tid >> 4);
      int sw7 = row & 7;
      int pos = (cf & 8) | ((cf & 7) ^ sw7);
      float4 vv = *(const float4*)(Xf + (row << 6) + (pos << 2));
      int cb = h2 * 8 + (cf >> 1);
      int bpos = (cb & 8) | ((cb & 7) ^ sw7);
      uint2 xu = *(const uint2*)(x1 + (((long)(m0 + row)) << 7) + (bpos << 3) + ((cf & 1) << 2));
      unsigned short* us = (unsigned short*)&xu;
      float ov[4];
      ov[0] = vv.x + bflo((uint32)us[0]);
      ov[1] = vv.y + bflo((uint32)us[1]);
      ov[2] = vv.z + bflo((uint32)us[2]);
      ov[3] = vv.w + bflo((uint32)us[3]);
      *(float4*)(out + ((long)asrc[row] << 7) + h2 * 64 + (cf << 2)) = *(float4*)ov;
    }
  }
}

// ---------- swapped-operand 32x32 MFMA attention, 13 waves, no max-track ------
// lrun is a pure sum (no rescale) -> cross-lane reduce deferred to after loop.
__global__ __launch_bounds__(832) void k_attn_mfma(
    const short* __restrict__ Q,   // [wh][n][32], pre-scaled by 1/sqrt(d)*log2e
    const short* __restrict__ Kk,  // [wh][n][32]
    const short* __restrict__ Vv,  // [wh][n][32]
    short* __restrict__ aout) {    // [wrow][128] bf16, SWIZZLED
  int wh = blockIdx.x, win = wh >> 2, head = wh & 3;
  __shared__ short Ks[NSEQ * 32];        // XOR-swizzled rows, 64 B stride
  __shared__ short Vs[32 * VSTR];        // [d][tok]; cols >=392 zero
  int tid = threadIdx.x;
  int lane = tid & 63, w = tid >> 6;     // w = 0..12 : one q-tile per wave
  int ql = lane & 31, h = lane >> 5;

  const uint4* Kg4 = (const uint4*)(Kk + (long)wh * NSEQ * DHEAD);
  for (int i = tid; i < 1568; i += 832) {
    int b = i * 16; b ^= ((b >> 6) & 7) << 4;
    *(uint4*)((char*)Ks + b) = Kg4[i];
  }
  const uint32* Vg = (const uint32*)(Vv + (long)wh * NSEQ * DHEAD);
  for (int i = tid; i < NSEQ * 16; i += 832) {
    int tok = i >> 4, dp = i & 15;
    uint32 u = Vg[i];
    Vs[(2 * dp) * VSTR + tok] = (short)(u & 0xffff);
    Vs[(2 * dp + 1) * VSTR + tok] = (short)(u >> 16);
  }
  if (tid < 224) {                        // zero pad cols 392..419 (28 per row)
    int r = tid >> 3, c7 = tid & 7;
    if (c7 < 7) *(uint2*)&Vs[r * VSTR + 392 + c7 * 4] = make_uint2(0, 0);
  }
  if (tid >= 224 && tid < 448) {
    int t2 = tid - 224;
    int r = 28 + (t2 >> 3), c7 = t2 & 7;
    if (c7 < 7 && r < 32) *(uint2*)&Vs[r * VSTR + 392 + c7 * 4] = make_uint2(0, 0);
  }
  __syncthreads();

  int q0 = w * 32;                        // tile 12 has 8 valid rows
  int qrow = q0 + ql; if (qrow > NSEQ - 1) qrow = NSEQ - 1;
  const short* Qr = Q + ((long)wh * NSEQ + qrow) * DHEAD;
  bf16x8 qf0 = *(const bf16x8*)(Qr + h * 8);
  bf16x8 qf1 = *(const bf16x8*)(Qr + 16 + h * 8);
  f32x16 o;
  #pragma unroll
  for (int r = 0; r < 16; r++) o[r] = 0.f;
  float lrun = 0.f;

  for (int c = 0; c < 13; c++) {
    int kb = c * 32;
    int krow = kb + ql;
    int sw = (krow & 7) << 4;
    int b0 = krow * 64 + h * 16;
    bf16x8 kf0 = *(const bf16x8*)((char*)Ks + (b0 ^ sw));
    bf16x8 kf1 = *(const bf16x8*)((char*)Ks + ((b0 + 32) ^ sw));
    f32x16 st;
    #pragma unroll
    for (int r = 0; r < 16; r++) st[r] = 0.f;
    __builtin_amdgcn_s_setprio(1);
    st = __builtin_amdgcn_mfma_f32_32x32x16_bf16(kf0, qf0, st, 0, 0, 0);
    st = __builtin_amdgcn_mfma_f32_32x32x16_bf16(kf1, qf1, st, 0, 0, 0);
    __builtin_amdgcn_s_setprio(0);
    if (c == 12) {
      #pragma unroll
      for (int r = 4; r < 16; r++) st[r] = -10000.f;   // exp2 -> 0
    }
    #pragma unroll
    for (int r = 0; r < 16; r++) { st[r] = fexp2(st[r]); lrun += st[r]; }
    #pragma unroll
    for (int s = 0; s < 2; s++) {
      if (s == 1 && c == 12) break;
      uint32 z0, z1, z2, z3;
      float p0 = st[8 * s + 0], p1 = st[8 * s + 1], p2 = st[8 * s + 2], p3 = st[8 * s + 3];
      float p4 = st[8 * s + 4], p5 = st[8 * s + 5], p6 = st[8 * s + 6], p7 = st[8 * s + 7];
      asm("v_cvt_pk_bf16_f32 %0, %1, %2" : "=v"(z0) : "v"(p0), "v"(p1));
      asm("v_cvt_pk_bf16_f32 %0, %1, %2" : "=v"(z1) : "v"(p2), "v"(p3));
      asm("v_cvt_pk_bf16_f32 %0, %1, %2" : "=v"(z2) : "v"(p4), "v"(p5));
      asm("v_cvt_pk_bf16_f32 %0, %1, %2" : "=v"(z3) : "v"(p6), "v"(p7));
      asm("v_permlane32_swap_b32 %0, %1" : "+v"(z0), "+v"(z2));
      asm("v_permlane32_swap_b32 %0, %1" : "+v"(z1), "+v"(z3));
      union { uint32 u[4]; bf16x8 v; } pb;
      pb.u[0] = z0; pb.u[1] = z1; pb.u[2] = z2; pb.u[3] = z3;
      bf16x8 vf = *(const bf16x8*)&Vs[ql * VSTR + kb + 16 * s + 8 * h];
      __builtin_amdgcn_s_setprio(1);
      o = __builtin_amdgcn_mfma_f32_32x32x16_bf16(vf, pb.v, o, 0, 0, 0);
      __builtin_amdgcn_s_setprio(0);
    }
  }
  lrun += __shfl_xor(lrun, 32);           // single deferred cross-lane reduce
  if (q0 + ql < NSEQ) {
    float inv = 1.0f / lrun;
    int qq = q0 + ql;
    long rowb = ((long)win * NSEQ + qq) * 256;   // byte base; (wrow&7)==(qq&7)
    int sw7 = qq & 7;
    #pragma unroll
    for (int rr = 0; rr < 8; rr++) {
      int r = 2 * rr;
      int d = (r & 3) + 8 * (r >> 2) + 4 * h;
      float a0 = o[r] * inv, a1 = o[r + 1] * inv;
      uint32 pk;
      asm("v_cvt_pk_bf16_f32 %0, %1, %2" : "=v"(pk) : "v"(a0), "v"(a1));
      int ch = head * 32 + d;
      int bo = (((ch >> 3) ^ sw7) << 4) + ((ch & 7) << 1);
      *(uint32*)((char*)aout + rowb + bo) = pk;
    }
  }
}

extern "C" void kernel_launch(void* const* d_in, const int* in_sizes, int n_in,
                              void* d_out, int out_size, void* d_ws, size_t ws_size,
                              hipStream_t stream) {
  const float* x    = (const float*)d_in[0];
  const float* n1g  = (const float*)d_in[1];
  const float* n1b  = (const float*)d_in[2];
  const float* qkvw = (const float*)d_in[3];
  const float* qkvb = (const float*)d_in[4];
  const float* projw= (const float*)d_in[5];
  const float* projb= (const float*)d_in[6];
  const float* dww  = (const float*)d_in[7];
  const float* dwb  = (const float*)d_in[8];
  const float* n2g  = (const float*)d_in[9];
  const float* n2b  = (const float*)d_in[10];
  const float* fc1w = (const float*)d_in[11];
  const float* fc1b = (const float*)d_in[12];
  const float* fc2w = (const float*)d_in[13];
  const float* fc2b = (const float*)d_in[14];

  char* ws = (char*)d_ws;
  short* wb_q = (short*)(ws + 0);              // 49152 sh
  short* wb_p = wb_q + 49152;
  short* wb_1 = wb_p + 16384;
  short* wb_2 = wb_1 + 65536;                  // end 393216 B
  short* xnb  = (short*)(ws + 393216);         // 12.8MB bf16 [-> aout -> hid p0]
  short* xs16 = (short*)(ws + 13238272);       // 12.8MB bf16 xsum [-> hid p1]
  short* Qb   = (short*)(ws + 38928384);       // 12.8MB      [-> x1]
  short* Kb   = (short*)(ws + 51773440);       // 12.8MB      [-> hid p3]
  short* Vb   = (short*)(ws + 64618496);       // 12.8MB      [-> xm]
  short* aoutb = xnb;
  short* x1b   = Qb;
  short* xmb   = Vb;
  short* hid0  = xnb;
  short* hid1  = (short*)(ws + 13238272);
  short* hid2  = (short*)(ws + 26083328);
  short* hid3  = Kb;

  k_prep<<<1792, 256, 0, stream>>>(qkvw, projw, fc1w, fc2w, wb_q, x, n1g, n1b, xnb);
  k_dwconv<<<(NTOK * 16) / 256, 256, 0, stream>>>(xnb, x, dww, dwb, xs16);
  k_gemm_mfma<64, 3, 384, 128, 0><<<2352, 256, 0, stream>>>(
      xnb, wb_q, qkvb, nullptr, nullptr, nullptr,
      nullptr, nullptr, nullptr, nullptr, Qb, Kb, Vb);
  k_attn_mfma<<<NWIN * NHEAD, 832, 0, stream>>>(Qb, Kb, Vb, aoutb);
  k_gemm_mfma<64, 1, 128, 128, 1><<<784, 256, 0, stream>>>(
      aoutb, wb_p, projb, xs16, n2g, n2b,
      nullptr, nullptr, nullptr, nullptr, x1b, xmb, nullptr);
  k_gemm_mfma<64, 4, 512, 128, 2><<<3136, 256, 0, stream>>>(
      xmb, wb_1, fc1b, nullptr, nullptr, nullptr,
      hid0, hid1, hid2, hid3, nullptr, nullptr, nullptr);
  k_fc2<<<784, 256, 0, stream>>>(
      x1b, wb_2, fc2b, hid0, hid1, hid2, hid3, (float*)d_out);
}

// Round 17
// 127.187 us; speedup vs baseline: 1.0295x; 1.0044x over previous
//
#include <hip/hip_runtime.h>
#include <hip/hip_bf16.h>

#define NB 2
#define ND 8
#define NHH 56
#define NWW 56
#define NC 128
#define NHEAD 4
#define DHEAD 32
#define NSEQ 392            // 8*7*7
#define NWIN 128            // 2*8*8
#define NTOK (NB*ND*NHH*NWW) // 50176
#define NHID 512
#define EPSV 1e-5f
#define PIECE 12544          // hid piece rows (4 pieces of 12544*512 bf16)
#define VSTR 420             // V LDS stride (210 dwords ≡ 18 mod 32 -> 2-way, free)

typedef unsigned int uint32;
typedef __attribute__((ext_vector_type(8))) short bf16x8;
typedef __attribute__((ext_vector_type(4))) float f32x4;
typedef __attribute__((ext_vector_type(16))) float f32x16;

__device__ __forceinline__ short f2bf(float x) {
  __hip_bfloat16 h = __float2bfloat16(x);
  return *reinterpret_cast<short*>(&h);
}
__device__ __forceinline__ float bflo(uint32 u) { return __uint_as_float(u << 16); }
__device__ __forceinline__ float bfhi(uint32 u) { return __uint_as_float(u & 0xffff0000u); }
__device__ __forceinline__ float fexp2(float x) {
  float e; asm("v_exp_f32 %0, %1" : "=v"(e) : "v"(x)); return e;
}

// windowed token index -> source spatial token index
__device__ __forceinline__ int win_to_src(int grow) {
  int win = grow / NSEQ, n = grow % NSEQ;
  int b = win >> 6, gh = (win >> 3) & 7, gw = win & 7;
  int d = n / 49, rem = n % 49;
  int p = rem / 7, q = rem % 7;
  int h = p * 8 + gh, w = q * 8 + gw;
  return ((b * ND + d) * NHH + h) * NWW + w;
}

#define GLDS(gp, lp) \
  __builtin_amdgcn_global_load_lds( \
      (const __attribute__((address_space(1))) void*)(gp), \
      (__attribute__((address_space(3))) void*)(lp), 16, 0, 0)

// ---- merged prep: blocks [0,768) convert weights (pre-swizzled bf16);
//      blocks [768,1792) do LayerNorm1 on WINDOWED rows -> swizzled bf16 ------
__global__ __launch_bounds__(256) void k_prep(
    const float* __restrict__ qkvw, const float* __restrict__ projw,
    const float* __restrict__ fc1w, const float* __restrict__ fc2w,
    short* __restrict__ wout,
    const float* __restrict__ xin, const float* __restrict__ g,
    const float* __restrict__ bsh, short* __restrict__ xout) {
  if (blockIdx.x < 768) {
    int i = blockIdx.x * 256 + threadIdx.x;   // 196608 total
    float v; int n, k, K, base;
    if (i < 49152)       { v = qkvw[i];          n = i >> 7;          k = i & 127;   K = 128; base = 0; }
    else if (i < 65536)  { int l = i - 49152;  v = projw[l]; n = l >> 7; k = l & 127; K = 128; base = 49152; }
    else if (i < 131072) { int l = i - 65536;  v = fc1w[l];  n = l >> 7; k = l & 127; K = 128; base = 65536; }
    else                 { int l = i - 131072; v = fc2w[l];  n = l >> 9; k = l & 511; K = 512; base = 131072; }
    int k2 = (((k >> 3) ^ (n & 7)) << 3) | (k & 7);
    wout[base + n * K + k2] = f2bf(v);
    return;
  }
  int w = threadIdx.x >> 6, lane = threadIdx.x & 63;
  float g0 = g[2 * lane], g1 = g[2 * lane + 1];
  float b0 = bsh[2 * lane], b1 = bsh[2 * lane + 1];
  for (int r = (blockIdx.x - 768) * 4 + w; r < NTOK; r += 4096) {
    int src = win_to_src(r);
    float2 v = *(const float2*)(xin + (long)src * NC + lane * 2);
    float s = v.x + v.y, s2 = v.x * v.x + v.y * v.y;
    #pragma unroll
    for (int m = 1; m < 64; m <<= 1) { s += __shfl_xor(s, m); s2 += __shfl_xor(s2, m); }
    float mu = s * (1.f / NC);
    float var = s2 * (1.f / NC) - mu * mu;
    float rr = rsqrtf(var + EPSV);
    uint32 p0 = (unsigned short)f2bf((v.x - mu) * rr * g0 + b0);
    uint32 p1 = (unsigned short)f2bf((v.y - mu) * rr * g1 + b1);
    int pos = (((lane >> 2) ^ (r & 7)) << 4) + ((lane & 3) << 2);  // byte in row
    *(uint32*)((char*)xout + (long)r * 256 + pos) = p0 | (p1 << 16);
  }
}

// ---- MERGED qkv GEMM + depthwise conv (independent work, one launch) --------
// blocks [0,2352): qkv — BM=64, NT=3, XCD-aware; Q(scaled*log2e)/K/V out
// blocks [2352,5488): dwconv — 8 ch/thread; xsum = x + conv -> bf16
__global__ __launch_bounds__(256) void k_qkv_dw(
    const short* __restrict__ A, const short* __restrict__ Wb,
    const float* __restrict__ bias,
    short* __restrict__ Qo, short* __restrict__ Ko, short* __restrict__ Vo,
    const float* __restrict__ xorig, const float* __restrict__ dwgt,
    const float* __restrict__ dbias, short* __restrict__ xsout) {
  __shared__ char S[24576];                 // qkv path: A 8K | B 16K
  int tid = threadIdx.x;
  if (blockIdx.x >= 2352) {
    // ---------------- dwconv path ----------------
    int idx = (blockIdx.x - 2352) * 256 + tid;      // over NTOK*16
    int c = idx & 15;                                // 8-channel chunk
    int wr = idx >> 4;                               // windowed row
    int win = wr / NSEQ, n = wr % NSEQ;
    int b = win >> 6, gh = (win >> 3) & 7, gw = win & 7;
    int d = n / 49, rem = n % 49;
    int p = rem / 7, q = rem % 7;
    int h = p * 8 + gh, w = q * 8 + gw;
    int bd = b * ND + d;
    float acc[8];
    {
      float4 b0 = *(const float4*)(dbias + 8 * c);
      float4 b1 = *(const float4*)(dbias + 8 * c + 4);
      acc[0] = b0.x; acc[1] = b0.y; acc[2] = b0.z; acc[3] = b0.w;
      acc[4] = b1.x; acc[5] = b1.y; acc[6] = b1.z; acc[7] = b1.w;
    }
    #pragma unroll
    for (int kh = 0; kh < 3; kh++) {
      int hh = h + kh - 1;
      if (hh < 0 || hh >= NHH) continue;
      #pragma unroll
      for (int kw = 0; kw < 3; kw++) {
        int ww = w + kw - 1;
        if (ww < 0 || ww >= NWW) continue;
        int wr2 = ((b << 6) + ((hh & 7) << 3) + (ww & 7)) * NSEQ
                + d * 49 + (hh >> 3) * 7 + (ww >> 3);
        int bo = (c ^ (wr2 & 7)) << 4;
        uint4 u = *(const uint4*)((const char*)A + (long)wr2 * 256 + bo);
        unsigned short* us = (unsigned short*)&u;
        const float* wp = dwgt + (kh * 3 + kw) * NC + 8 * c;
        float4 w0 = *(const float4*)(wp);
        float4 w1 = *(const float4*)(wp + 4);
        float wv[8] = {w0.x, w0.y, w0.z, w0.w, w1.x, w1.y, w1.z, w1.w};
        #pragma unroll
        for (int e = 0; e < 8; e++) acc[e] += bflo((uint32)us[e]) * wv[e];
      }
    }
    int src = (bd * NHH + h) * NWW + w;
    float4 x0 = *(const float4*)(xorig + ((long)src << 7) + 8 * c);
    float4 x1 = *(const float4*)(xorig + ((long)src << 7) + 8 * c + 4);
    float xv[8] = {x0.x, x0.y, x0.z, x0.w, x1.x, x1.y, x1.z, x1.w};
    short ov[8];
    #pragma unroll
    for (int e = 0; e < 8; e++) ov[e] = f2bf(acc[e] + xv[e]);
    *(uint4*)(xsout + ((long)wr << 7) + 8 * c) = *(uint4*)ov;
    return;
  }
  // ---------------- qkv path (BM=64, NT=3, K=128) ----------------
  int bid = blockIdx.x;
  int xcd = bid & 7, slot = bid >> 3;
  int mq = slot / 3, nt = slot - mq * 3;
  int m0 = (mq * 8 + xcd) * 64;
  int n0 = nt * 128;
  int lane = tid & 63, w = tid >> 6;
  int wm = w & 1, wn = w >> 1;
  int c16 = lane & 15, g = lane >> 4;

  f32x4 acc[2][4];
  #pragma unroll
  for (int i = 0; i < 2; i++)
    #pragma unroll
    for (int j = 0; j < 4; j++) acc[i][j] = f32x4{0.f, 0.f, 0.f, 0.f};

  for (int ks = 0; ks < 2; ks++) {
    int k0 = ks * 64;
    if (ks > 0) __syncthreads();
    #pragma unroll
    for (int i = 0; i < 2; i++) {            // A: 512 units
      int idx = tid + i * 256;
      int row = idx >> 3, colq = idx & 7;
      GLDS(A + (long)(m0 + row) * 128 + k0 + colq * 8, S + (idx << 4));
    }
    #pragma unroll
    for (int i = 0; i < 4; i++) {            // B: 128 rows
      int idx = tid + i * 256;
      int row = idx >> 3, colq = idx & 7;
      GLDS(Wb + (long)(n0 + row) * 128 + k0 + colq * 8, S + 8192 + (idx << 4));
    }
    asm volatile("s_waitcnt vmcnt(0)" ::: "memory");
    __syncthreads();
    #pragma unroll
    for (int kk = 0; kk < 2; kk++) {
      bf16x8 af[2], bfr[4];
      #pragma unroll
      for (int i = 0; i < 2; i++) {
        int ra = wm * 32 + i * 16 + c16;
        int ba = (ra << 7) + ((g + kk * 4) << 4); ba ^= ((ra & 7) << 4);
        af[i] = *(const bf16x8*)(S + ba);
      }
      #pragma unroll
      for (int j = 0; j < 4; j++) {
        int rb = wn * 64 + j * 16 + c16;
        int bb = (rb << 7) + ((g + kk * 4) << 4); bb ^= ((rb & 7) << 4);
        bfr[j] = *(const bf16x8*)(S + 8192 + bb);
      }
      #pragma unroll
      for (int i = 0; i < 2; i++)
        #pragma unroll
        for (int j = 0; j < 4; j++)
          acc[i][j] = __builtin_amdgcn_mfma_f32_16x16x32_bf16(af[i], bfr[j], acc[i][j], 0, 0, 0);
    }
  }
  __syncthreads();

  short* X1 = (short*)S;
  float qscale = (n0 == 0) ? 0.2550348658f : 1.0f;
  #pragma unroll
  for (int i = 0; i < 2; i++) {
    #pragma unroll
    for (int r = 0; r < 4; r++) {
      int row = wm * 32 + i * 16 + g * 4 + r;
      int sw7 = row & 7;
      #pragma unroll
      for (int j = 0; j < 4; j++) {
        int nl = wn * 64 + j * 16 + c16;
        float v = (acc[i][j][r] + bias[n0 + nl]) * qscale;
        int ch = nl >> 3;
        int pos = (ch & 8) | ((ch & 7) ^ sw7);
        X1[(row << 7) + (pos << 3) + (nl & 7)] = f2bf(v);
      }
    }
  }
  __syncthreads();
  int cc = tid & 15;
  #pragma unroll
  for (int it8 = 0; it8 < 4; it8++) {
    int row = it8 * 16 + (tid >> 4);
    int sw7 = row & 7;
    int pos = (cc & 8) | ((cc & 7) ^ sw7);
    uint4 val = *(const uint4*)(X1 + (row << 7) + (pos << 3));
    int m = m0 + row;
    int win = m / NSEQ, tok = m - win * NSEQ;
    short* OUT = (n0 == 0) ? Qo : (n0 == 128) ? Ko : Vo;
    int head = cc >> 2, dim0 = (cc & 3) << 3;
    *(uint4*)(OUT + ((((long)(win * NHEAD + head)) * NSEQ + tok) << 5) + dim0) = val;
  }
}

// ------------- MFMA GEMM: C[M,N] = A[M,K] * W[N,K]^T, BMx128 tile, BK=64 ------
// MODE 1: proj — x1 = xsum16 + bias + val -> O0 bf16 swz; fused LN2 -> O1 swz
// MODE 2: fc1 — tanh-gelu -> hid pieces h0..h3 (row-swizzled)
template <int BM, int NT, int NDIM, int KDIM, int MODE>
__global__ __launch_bounds__(256) void k_gemm_mfma(
    const short* __restrict__ A, const short* __restrict__ Wb,
    const float* __restrict__ bias, const short* __restrict__ xsum16,
    const float* __restrict__ g2, const float* __restrict__ b2,
    short* __restrict__ h0, short* __restrict__ h1,
    short* __restrict__ h2p, short* __restrict__ h3,
    void* __restrict__ O0, void* __restrict__ O1, void* __restrict__ O2) {
  constexpr int ABYTES = BM * 128;          // A tile bytes per BK=64 step
  constexpr int MI = BM / 32;               // row-fragments per wave
  __shared__ char S[ABYTES + 16384];        // A | B staging; reused post-loop
  int tid = threadIdx.x;
  int m0, n0;
  if constexpr (NT > 1) {
    int bid = blockIdx.x;
    int xcd = bid & 7, slot = bid >> 3;
    int mq = slot / NT, nt = slot - mq * NT;
    m0 = (mq * 8 + xcd) * BM;
    n0 = nt * 128;
  } else {
    m0 = blockIdx.x * BM;
    n0 = 0;
  }
  int lane = tid & 63, w = tid >> 6;
  int wm = w & 1, wn = w >> 1;
  int c16 = lane & 15, g = lane >> 4;

  f32x4 acc[MI][4];
  #pragma unroll
  for (int i = 0; i < MI; i++)
    #pragma unroll
    for (int j = 0; j < 4; j++) acc[i][j] = f32x4{0.f, 0.f, 0.f, 0.f};

  const int KSTEPS = KDIM / 64;
  for (int ks = 0; ks < KSTEPS; ks++) {
    int k0 = ks * 64;
    if (ks > 0) __syncthreads();
    #pragma unroll
    for (int i = 0; i < BM / 32; i++) {      // A: BM*8 units / 256 threads
      int idx = tid + i * 256;
      int row = idx >> 3, colq = idx & 7;
      GLDS(A + (long)(m0 + row) * KDIM + k0 + colq * 8, S + (idx << 4));
    }
    #pragma unroll
    for (int i = 0; i < 4; i++) {            // B: 128 rows
      int idx = tid + i * 256;
      int row = idx >> 3, colq = idx & 7;
      GLDS(Wb + (long)(n0 + row) * KDIM + k0 + colq * 8, S + ABYTES + (idx << 4));
    }
    asm volatile("s_waitcnt vmcnt(0)" ::: "memory");
    __syncthreads();
    #pragma unroll
    for (int kk = 0; kk < 2; kk++) {
      bf16x8 af[MI], bfr[4];
      #pragma unroll
      for (int i = 0; i < MI; i++) {
        int ra = wm * (BM / 2) + i * 16 + c16;
        int ba = (ra << 7) + ((g + kk * 4) << 4); ba ^= ((ra & 7) << 4);
        af[i] = *(const bf16x8*)(S + ba);
      }
      #pragma unroll
      for (int j = 0; j < 4; j++) {
        int rb = wn * 64 + j * 16 + c16;
        int bb = (rb << 7) + ((g + kk * 4) << 4); bb ^= ((rb & 7) << 4);
        bfr[j] = *(const bf16x8*)(S + ABYTES + bb);
      }
      #pragma unroll
      for (int i = 0; i < MI; i++)
        #pragma unroll
        for (int j = 0; j < 4; j++)
          acc[i][j] = __builtin_amdgcn_mfma_f32_16x16x32_bf16(af[i], bfr[j], acc[i][j], 0, 0, 0);
    }
  }
  __syncthreads();                           // staging dead; S reusable

  // ---- write bf16 C tile into S with row-XOR chunk swizzle ----
  short* X1 = (short*)S;
  #pragma unroll
  for (int i = 0; i < MI; i++) {
    #pragma unroll
    for (int r = 0; r < 4; r++) {
      int row = wm * (BM / 2) + i * 16 + g * 4 + r;
      int sw7 = row & 7;
      #pragma unroll
      for (int j = 0; j < 4; j++) {
        int nl = wn * 64 + j * 16 + c16;
        float v = acc[i][j][r] + bias[n0 + nl];
        if constexpr (MODE == 2) {
          float u = v * (0.7978845608f + 0.035677408f * v * v);
          u = fmaxf(u, -15.f);
          float t = fexp2(u * -2.885390082f);
          v = 0.5f * v * (1.f + (1.f - t) / (1.f + t));
        }
        int ch = nl >> 3;
        int pos = (ch & 8) | ((ch & 7) ^ sw7);
        X1[(row << 7) + (pos << 3) + (nl & 7)] = f2bf(v);
      }
    }
  }
  __syncthreads();
  // ---- read + coalesced stores: 16 lanes cover one row's 16 chunks ----
  int cc = tid & 15;
  #pragma unroll
  for (int it8 = 0; it8 < BM / 16; it8++) {
    int row = it8 * 16 + (tid >> 4);
    int sw7 = row & 7;
    int pos = (cc & 8) | ((cc & 7) ^ sw7);
    uint4 val = *(const uint4*)(X1 + (row << 7) + (pos << 3));
    if constexpr (MODE == 2) {
      int pco = m0 / PIECE;
      short* hpO = (pco == 0) ? h0 : (pco == 1) ? h1 : (pco == 2) ? h2p : h3;
      int mloc = m0 - pco * PIECE + row;
      *(uint4*)(hpO + ((long)mloc << 9) + n0 + (pos << 3)) = val;  // swz pos
    } else {  // MODE 1: add xsum, LN2 stats over the 16-lane row, dual store
      long m = m0 + row;
      uint4 xs = *(const uint4*)(xsum16 + (m << 7) + (cc << 3));
      unsigned short* tv = (unsigned short*)&val;
      unsigned short* us = (unsigned short*)&xs;
      float xv[8];
      float s = 0.f, s2 = 0.f;
      #pragma unroll
      for (int e = 0; e < 8; e++) {
        xv[e] = bflo((uint32)tv[e]) + bflo((uint32)us[e]);
        s += xv[e]; s2 += xv[e] * xv[e];
      }
      #pragma unroll
      for (int mm = 1; mm < 16; mm <<= 1) { s += __shfl_xor(s, mm); s2 += __shfl_xor(s2, mm); }
      float mu = s * (1.f / NC);
      float var = s2 * (1.f / NC) - mu * mu;
      float rr2 = rsqrtf(var + EPSV);
      float4 gv0 = *(const float4*)(g2 + cc * 8);
      float4 gv1 = *(const float4*)(g2 + cc * 8 + 4);
      float4 bv0 = *(const float4*)(b2 + cc * 8);
      float4 bv1 = *(const float4*)(b2 + cc * 8 + 4);
      float gg[8] = {gv0.x, gv0.y, gv0.z, gv0.w, gv1.x, gv1.y, gv1.z, gv1.w};
      float bb[8] = {bv0.x, bv0.y, bv0.z, bv0.w, bv1.x, bv1.y, bv1.z, bv1.w};
      short xo[8], lo[8];
      #pragma unroll
      for (int e = 0; e < 8; e++) {
        xo[e] = f2bf(xv[e]);
        lo[e] = f2bf((xv[e] - mu) * rr2 * gg[e] + bb[e]);
      }
      *(uint4*)((short*)O0 + (m << 7) + (pos << 3)) = *(uint4*)xo;  // x1 swz
      *(uint4*)((short*)O1 + (m << 7) + (pos << 3)) = *(uint4*)lo;  // xm swz
    }
  }
}

// ------------- fc2: BM=64, K=512, double-buffered (counted vmcnt) -------------
__global__ __launch_bounds__(256) void k_fc2(
    const short* __restrict__ x1, const short* __restrict__ w2,
    const float* __restrict__ bias,
    const short* __restrict__ h0, const short* __restrict__ h1,
    const short* __restrict__ h2p, const short* __restrict__ h3,
    float* __restrict__ out) {
  __shared__ char S[2][24576];              // each: A 8K | B 16K
  __shared__ int asrc[64];
  int tid = threadIdx.x;
  int m0 = blockIdx.x * 64;
  int lane = tid & 63, w = tid >> 6;
  int wm = w & 1, wn = w >> 1;
  int c16 = lane & 15, g = lane >> 4;
  if (tid < 64) asrc[tid] = win_to_src(m0 + tid);
  int pc = m0 / PIECE;
  const short* hpA = (pc == 0) ? h0 : (pc == 1) ? h1 : (pc == 2) ? h2p : h3;
  int arow0 = m0 - pc * PIECE;

  f32x4 acc[2][4];
  #pragma unroll
  for (int i = 0; i < 2; i++)
    #pragma unroll
    for (int j = 0; j < 4; j++) acc[i][j] = f32x4{0.f, 0.f, 0.f, 0.f};

#define FC2_STAGE(ks, buf) do {                                               \
    int k0_ = (ks) * 64;                                                      \
    _Pragma("unroll")                                                         \
    for (int i_ = 0; i_ < 2; i_++) {                                          \
      int idx_ = tid + i_ * 256;                                              \
      int row_ = idx_ >> 3, colq_ = idx_ & 7;                                 \
      GLDS(hpA + (long)(arow0 + row_) * 512 + k0_ + colq_ * 8,                \
           S[buf] + (idx_ << 4));                                             \
    }                                                                         \
    _Pragma("unroll")                                                         \
    for (int i_ = 0; i_ < 4; i_++) {                                          \
      int idx_ = tid + i_ * 256;                                              \
      int row_ = idx_ >> 3, colq_ = idx_ & 7;                                 \
      GLDS(w2 + (long)row_ * 512 + k0_ + colq_ * 8,                           \
           S[buf] + 8192 + (idx_ << 4));                                      \
    }                                                                         \
  } while (0)

  FC2_STAGE(0, 0);
  for (int ks = 0; ks < 8; ks++) {
    int cur = ks & 1;
    if (ks < 7) FC2_STAGE(ks + 1, cur ^ 1);
    if (ks < 7) asm volatile("s_waitcnt vmcnt(6)" ::: "memory");
    else        asm volatile("s_waitcnt vmcnt(0)" ::: "memory");
    __builtin_amdgcn_s_barrier();
    __builtin_amdgcn_sched_barrier(0);
    #pragma unroll
    for (int kk = 0; kk < 2; kk++) {
      bf16x8 af[2], bfr[4];
      #pragma unroll
      for (int i = 0; i < 2; i++) {
        int ra = wm * 32 + i * 16 + c16;
        int ba = (ra << 7) + ((g + kk * 4) << 4); ba ^= ((ra & 7) << 4);
        af[i] = *(const bf16x8*)(S[cur] + ba);
      }
      #pragma unroll
      for (int j = 0; j < 4; j++) {
        int rb = wn * 64 + j * 16 + c16;
        int bb = (rb << 7) + ((g + kk * 4) << 4); bb ^= ((rb & 7) << 4);
        bfr[j] = *(const bf16x8*)(S[cur] + 8192 + bb);
      }
      #pragma unroll
      for (int i = 0; i < 2; i++)
        #pragma unroll
        for (int j = 0; j < 4; j++)
          acc[i][j] = __builtin_amdgcn_mfma_f32_16x16x32_bf16(af[i], bfr[j], acc[i][j], 0, 0, 0);
    }
    __builtin_amdgcn_s_barrier();            // all waves done with S[cur]
    __builtin_amdgcn_sched_barrier(0);
  }
#undef FC2_STAGE

  // ---- f32 out in two 64-col half-passes through S[0] ----
  float* Xf = (float*)S[0];
  #pragma unroll
  for (int h2 = 0; h2 < 2; h2++) {
    if (h2 == 1) __syncthreads();
    if (wn == h2) {
      #pragma unroll
      for (int i = 0; i < 2; i++) {
        #pragma unroll
        for (int r = 0; r < 4; r++) {
          int row = wm * 32 + i * 16 + g * 4 + r;
          int sw7 = row & 7;
          #pragma unroll
          for (int j = 0; j < 4; j++) {
            int nl = j * 16 + c16;             // 0..63 within half
            int cf = nl >> 2;                  // f32 16B chunk 0..15
            int pos = (cf & 8) | ((cf & 7) ^ sw7);
            Xf[(row << 6) + (pos << 2) + (nl & 3)] = acc[i][j][r] + bias[h2 * 64 + nl];
          }
        }
      }
    }
    __syncthreads();
    int cf = tid & 15;
    #pragma unroll
    for (int it8 = 0; it8 < 4; it8++) {
      int row = it8 * 16 + (tid >> 4);
      int sw7 = row & 7;
      int pos = (cf & 8) | ((cf & 7) ^ sw7);
      float4 vv = *(const float4*)(Xf + (row << 6) + (pos << 2));
      int cb = h2 * 8 + (cf >> 1);
      int bpos = (cb & 8) | ((cb & 7) ^ sw7);
      uint2 xu = *(const uint2*)(x1 + (((long)(m0 + row)) << 7) + (bpos << 3) + ((cf & 1) << 2));
      unsigned short* us = (unsigned short*)&xu;
      float ov[4];
      ov[0] = vv.x + bflo((uint32)us[0]);
      ov[1] = vv.y + bflo((uint32)us[1]);
      ov[2] = vv.z + bflo((uint32)us[2]);
      ov[3] = vv.w + bflo((uint32)us[3]);
      *(float4*)(out + ((long)asrc[row] << 7) + h2 * 64 + (cf << 2)) = *(float4*)ov;
    }
  }
}

// ---------- swapped-operand 32x32 MFMA attention, 13 waves, no max-track ------
// lrun is a pure sum (no rescale) -> cross-lane reduce deferred to after loop.
__global__ __launch_bounds__(832) void k_attn_mfma(
    const short* __restrict__ Q,   // [wh][n][32], pre-scaled by 1/sqrt(d)*log2e
    const short* __restrict__ Kk,  // [wh][n][32]
    const short* __restrict__ Vv,  // [wh][n][32]
    short* __restrict__ aout) {    // [wrow][128] bf16, SWIZZLED
  int wh = blockIdx.x, win = wh >> 2, head = wh & 3;
  __shared__ short Ks[NSEQ * 32];        // XOR-swizzled rows, 64 B stride
  __shared__ short Vs[32 * VSTR];        // [d][tok]; cols >=392 zero
  int tid = threadIdx.x;
  int lane = tid & 63, w = tid >> 6;     // w = 0..12 : one q-tile per wave
  int ql = lane & 31, h = lane >> 5;

  const uint4* Kg4 = (const uint4*)(Kk + (long)wh * NSEQ * DHEAD);
  for (int i = tid; i < 1568; i += 832) {
    int b = i * 16; b ^= ((b >> 6) & 7) << 4;
    *(uint4*)((char*)Ks + b) = Kg4[i];
  }
  const uint32* Vg = (const uint32*)(Vv + (long)wh * NSEQ * DHEAD);
  for (int i = tid; i < NSEQ * 16; i += 832) {
    int tok = i >> 4, dp = i & 15;
    uint32 u = Vg[i];
    Vs[(2 * dp) * VSTR + tok] = (short)(u & 0xffff);
    Vs[(2 * dp + 1) * VSTR + tok] = (short)(u >> 16);
  }
  if (tid < 224) {                        // zero pad cols 392..419 (28 per row)
    int r = tid >> 3, c7 = tid & 7;
    if (c7 < 7) *(uint2*)&Vs[r * VSTR + 392 + c7 * 4] = make_uint2(0, 0);
  }
  if (tid >= 224 && tid < 448) {
    int t2 = tid - 224;
    int r = 28 + (t2 >> 3), c7 = t2 & 7;
    if (c7 < 7 && r < 32) *(uint2*)&Vs[r * VSTR + 392 + c7 * 4] = make_uint2(0, 0);
  }
  __syncthreads();

  int q0 = w * 32;                        // tile 12 has 8 valid rows
  int qrow = q0 + ql; if (qrow > NSEQ - 1) qrow = NSEQ - 1;
  const short* Qr = Q + ((long)wh * NSEQ + qrow) * DHEAD;
  bf16x8 qf0 = *(const bf16x8*)(Qr + h * 8);
  bf16x8 qf1 = *(const bf16x8*)(Qr + 16 + h * 8);
  f32x16 o;
  #pragma unroll
  for (int r = 0; r < 16; r++) o[r] = 0.f;
  float lrun = 0.f;

  for (int c = 0; c < 13; c++) {
    int kb = c * 32;
    int krow = kb + ql;
    int sw = (krow & 7) << 4;
    int b0 = krow * 64 + h * 16;
    bf16x8 kf0 = *(const bf16x8*)((char*)Ks + (b0 ^ sw));
    bf16x8 kf1 = *(const bf16x8*)((char*)Ks + ((b0 + 32) ^ sw));
    f32x16 st;
    #pragma unroll
    for (int r = 0; r < 16; r++) st[r] = 0.f;
    __builtin_amdgcn_s_setprio(1);
    st = __builtin_amdgcn_mfma_f32_32x32x16_bf16(kf0, qf0, st, 0, 0, 0);
    st = __builtin_amdgcn_mfma_f32_32x32x16_bf16(kf1, qf1, st, 0, 0, 0);
    __builtin_amdgcn_s_setprio(0);
    if (c == 12) {
      #pragma unroll
      for (int r = 4; r < 16; r++) st[r] = -10000.f;   // exp2 -> 0
    }
    #pragma unroll
    for (int r = 0; r < 16; r++) { st[r] = fexp2(st[r]); lrun += st[r]; }
    #pragma unroll
    for (int s = 0; s < 2; s++) {
      if (s == 1 && c == 12) break;
      uint32 z0, z1, z2, z3;
      float p0 = st[8 * s + 0], p1 = st[8 * s + 1], p2 = st[8 * s + 2], p3 = st[8 * s + 3];
      float p4 = st[8 * s + 4], p5 = st[8 * s + 5], p6 = st[8 * s + 6], p7 = st[8 * s + 7];
      asm("v_cvt_pk_bf16_f32 %0, %1, %2" : "=v"(z0) : "v"(p0), "v"(p1));
      asm("v_cvt_pk_bf16_f32 %0, %1, %2" : "=v"(z1) : "v"(p2), "v"(p3));
      asm("v_cvt_pk_bf16_f32 %0, %1, %2" : "=v"(z2) : "v"(p4), "v"(p5));
      asm("v_cvt_pk_bf16_f32 %0, %1, %2" : "=v"(z3) : "v"(p6), "v"(p7));
      asm("v_permlane32_swap_b32 %0, %1" : "+v"(z0), "+v"(z2));
      asm("v_permlane32_swap_b32 %0, %1" : "+v"(z1), "+v"(z3));
      union { uint32 u[4]; bf16x8 v; } pb;
      pb.u[0] = z0; pb.u[1] = z1; pb.u[2] = z2; pb.u[3] = z3;
      bf16x8 vf = *(const bf16x8*)&Vs[ql * VSTR + kb + 16 * s + 8 * h];
      __builtin_amdgcn_s_setprio(1);
      o = __builtin_amdgcn_mfma_f32_32x32x16_bf16(vf, pb.v, o, 0, 0, 0);
      __builtin_amdgcn_s_setprio(0);
    }
  }
  lrun += __shfl_xor(lrun, 32);           // single deferred cross-lane reduce
  if (q0 + ql < NSEQ) {
    float inv = 1.0f / lrun;
    int qq = q0 + ql;
    long rowb = ((long)win * NSEQ + qq) * 256;   // byte base; (wrow&7)==(qq&7)
    int sw7 = qq & 7;
    #pragma unroll
    for (int rr = 0; rr < 8; rr++) {
      int r = 2 * rr;
      int d = (r & 3) + 8 * (r >> 2) + 4 * h;
      float a0 = o[r] * inv, a1 = o[r + 1] * inv;
      uint32 pk;
      asm("v_cvt_pk_bf16_f32 %0, %1, %2" : "=v"(pk) : "v"(a0), "v"(a1));
      int ch = head * 32 + d;
      int bo = (((ch >> 3) ^ sw7) << 4) + ((ch & 7) << 1);
      *(uint32*)((char*)aout + rowb + bo) = pk;
    }
  }
}

extern "C" void kernel_launch(void* const* d_in, const int* in_sizes, int n_in,
                              void* d_out, int out_size, void* d_ws, size_t ws_size,
                              hipStream_t stream) {
  const float* x    = (const float*)d_in[0];
  const float* n1g  = (const float*)d_in[1];
  const float* n1b  = (const float*)d_in[2];
  const float* qkvw = (const float*)d_in[3];
  const float* qkvb = (const float*)d_in[4];
  const float* projw= (const float*)d_in[5];
  const float* projb= (const float*)d_in[6];
  const float* dww  = (const float*)d_in[7];
  const float* dwb  = (const float*)d_in[8];
  const float* n2g  = (const float*)d_in[9];
  const float* n2b  = (const float*)d_in[10];
  const float* fc1w = (const float*)d_in[11];
  const float* fc1b = (const float*)d_in[12];
  const float* fc2w = (const float*)d_in[13];
  const float* fc2b = (const float*)d_in[14];

  char* ws = (char*)d_ws;
  short* wb_q = (short*)(ws + 0);              // 49152 sh
  short* wb_p = wb_q + 49152;
  short* wb_1 = wb_p + 16384;
  short* wb_2 = wb_1 + 65536;                  // end 393216 B
  short* xnb  = (short*)(ws + 393216);         // 12.8MB bf16 [-> aout -> hid p0]
  short* xs16 = (short*)(ws + 13238272);       // 12.8MB bf16 xsum [-> hid p1]
  short* Qb   = (short*)(ws + 38928384);       // 12.8MB      [-> x1]
  short* Kb   = (short*)(ws + 51773440);       // 12.8MB      [-> hid p3]
  short* Vb   = (short*)(ws + 64618496);       // 12.8MB      [-> xm]
  short* aoutb = xnb;
  short* x1b   = Qb;
  short* xmb   = Vb;
  short* hid0  = xnb;
  short* hid1  = (short*)(ws + 13238272);
  short* hid2  = (short*)(ws + 26083328);
  short* hid3  = Kb;

  k_prep<<<1792, 256, 0, stream>>>(qkvw, projw, fc1w, fc2w, wb_q, x, n1g, n1b, xnb);
  k_qkv_dw<<<5488, 256, 0, stream>>>(
      xnb, wb_q, qkvb, Qb, Kb, Vb, x, dww, dwb, xs16);
  k_attn_mfma<<<NWIN * NHEAD, 832, 0, stream>>>(Qb, Kb, Vb, aoutb);
  k_gemm_mfma<64, 1, 128, 128, 1><<<784, 256, 0, stream>>>(
      aoutb, wb_p, projb, xs16, n2g, n2b,
      nullptr, nullptr, nullptr, nullptr, x1b, xmb, nullptr);
  k_gemm_mfma<64, 4, 512, 128, 2><<<3136, 256, 0, stream>>>(
      xmb, wb_1, fc1b, nullptr, nullptr, nullptr,
      hid0, hid1, hid2, hid3, nullptr, nullptr, nullptr);
  k_fc2<<<784, 256, 0, stream>>>(
      x1b, wb_2, fc2b, hid0, hid1, hid2, hid3, (float*)d_out);
}